// Round 16
// baseline (246.128 us; speedup 1.0000x reference)
//
#include <hip/hip_runtime.h>
#include <stdint.h>

typedef __attribute__((ext_vector_type(8))) __bf16 bf16x8;
typedef __attribute__((ext_vector_type(16))) float f32x16;

__device__ __forceinline__ unsigned short f2bf(float f) {
  union { float f; unsigned int u; } v;
  v.f = f;
  unsigned int u = v.u;
  return (unsigned short)((u + 0x7FFFu + ((u >> 16) & 1u)) >> 16);
}

union BFrag { unsigned short u[8]; unsigned int w[4]; bf16x8 v; };

__device__ __forceinline__ f32x16 mfma32(bf16x8 a, bf16x8 b, f32x16 c) {
  return __builtin_amdgcn_mfma_f32_32x32x16_bf16(a, b, c, 0, 0, 0);
}

#define GLOAD_LDS16(gptr, lptr)                                                \
  __builtin_amdgcn_global_load_lds(                                           \
      (const __attribute__((address_space(1))) void*)(gptr),                  \
      (__attribute__((address_space(3))) void*)(lptr), 16, 0, 0)

// ---------------- x gather + fp32->bf16 (region-token order) ----------------
__global__ __launch_bounds__(256) void k_xgather(const float* __restrict__ x,
                                                 unsigned short* __restrict__ xb) {
  int idx = blockIdx.x * 256 + threadIdx.x;
  int m = idx >> 6;
  int seg = (idx & 63) << 3;
  int r = m >> 8, n = m & 255;
  int a = r / 12, b = r - a * 12;
  int ii = n >> 4, jj = n & 15;
  long g = (long)((a * 16 + ii) * 192 + b * 16 + jj);
  const float4* p = (const float4*)(x + g * 512 + seg);
  float4 v0 = p[0], v1 = p[1];
  union { unsigned short u[8]; int4 v; } o;
  o.u[0] = f2bf(v0.x); o.u[1] = f2bf(v0.y); o.u[2] = f2bf(v0.z); o.u[3] = f2bf(v0.w);
  o.u[4] = f2bf(v1.x); o.u[5] = f2bf(v1.y); o.u[6] = f2bf(v1.z); o.u[7] = f2bf(v1.w);
  *(int4*)(xb + (size_t)m * 512 + seg) = o.v;
}

// ---------------- plain fp32->bf16 ----------------
__global__ __launch_bounds__(256) void k_cvt(const float* __restrict__ s,
                                             unsigned short* __restrict__ d, int n8) {
  int i = blockIdx.x * 256 + threadIdx.x;
  if (i >= n8) return;
  const float4* p = (const float4*)(s + (size_t)i * 8);
  float4 a = p[0], b = p[1];
  union { unsigned short u[8]; int4 v; } o;
  o.u[0] = f2bf(a.x); o.u[1] = f2bf(a.y); o.u[2] = f2bf(a.z); o.u[3] = f2bf(a.w);
  o.u[4] = f2bf(b.x); o.u[5] = f2bf(b.y); o.u[6] = f2bf(b.z); o.u[7] = f2bf(b.w);
  *(int4*)(d + (size_t)i * 8) = o.v;
}

// ---------------- GEMM v2: 256x256 tile, BK=32, 4-buf LDS ring, counted vmcnt
// C[m][n] = sum_k A[m][k]*B[n][k]. 512 threads = 8 waves (2M x 4N), per-wave
// output 128x64 via acc[4][2] f32x16. Prefetch distance 2; s_waitcnt vmcnt(4)
// (never 0 mid-loop) + ONE raw s_barrier per iter. Buf b rewritten for tile
// t+4 at iter t+2 >= 2 collective barriers after its last read (iter t): safe.
// MODE 0: QKV epilogue (q scaled 0.125); MODE 1: proj epilogue (fp32 scatter).
template<int MODE, int NBN>
__global__ __launch_bounds__(512, 2) void k_gemm2(
    const unsigned short* __restrict__ A, const unsigned short* __restrict__ B,
    const float* __restrict__ bias,
    unsigned short* __restrict__ qb, unsigned short* __restrict__ kb,
    unsigned short* __restrict__ vtb, float* __restrict__ out) {
  extern __shared__ char lds[];
  int t = threadIdx.x;
  constexpr int NWG = NBN * 144;
  int d0 = blockIdx.x;
  int tl = (d0 & 7) * (NWG >> 3) + (d0 >> 3);
  int bm = tl / NBN, bn = tl % NBN;

  int w = t >> 6, lane = t & 63;
  int l31 = lane & 31, lh = lane >> 5;
  int wr = w >> 2, wc = w & 3;           // wave -> (M half, N quarter)

  int srow = t >> 2, sseg = t & 3;       // staging coords (128 rows/round)

  f32x16 acc[4][2];
#pragma unroll
  for (int i = 0; i < 4; ++i)
#pragma unroll
    for (int j = 0; j < 2; ++j)
#pragma unroll
      for (int e = 0; e < 16; ++e) acc[i][j][e] = 0.0f;

  const unsigned short* Ag0 = A + (size_t)(bm * 256) * 512;
  const unsigned short* Bg0 = B + (size_t)(bn * 256) * 512;

#define STAGE2(tile)                                                           \
  {                                                                            \
    char* buf_ = lds + ((tile) & 3) * 32768;                                   \
    _Pragma("unroll")                                                          \
    for (int r_ = 0; r_ < 2; ++r_) {                                           \
      int row_ = r_ * 128 + srow;                                              \
      int csw_ = (sseg ^ (row_ & 3)) << 3;                                     \
      GLOAD_LDS16(Ag0 + (size_t)row_ * 512 + (tile) * 32 + csw_,               \
                  buf_ + r_ * 8192 + t * 16);                                  \
      GLOAD_LDS16(Bg0 + (size_t)row_ * 512 + (tile) * 32 + csw_,               \
                  buf_ + 16384 + r_ * 8192 + t * 16);                          \
    }                                                                          \
  }

  STAGE2(0);
  STAGE2(1);
  asm volatile("s_waitcnt vmcnt(4)" ::: "memory");
  __builtin_amdgcn_s_barrier();

#pragma unroll
  for (int kt0 = 0; kt0 < 16; ++kt0) {
    if (kt0 < 14) STAGE2(kt0 + 2);
    const char* abuf = lds + (kt0 & 3) * 32768;
    const char* bbuf = abuf + 16384;
#pragma unroll
    for (int kt = 0; kt < 2; ++kt) {
      bf16x8 af[4], bfr[2];
#pragma unroll
      for (int mt = 0; mt < 4; ++mt) {
        int r = wr * 128 + mt * 32 + l31;
        af[mt] = *(const bf16x8*)(abuf + r * 64 + (((kt * 2 + lh) ^ (r & 3)) << 4));
      }
#pragma unroll
      for (int nt = 0; nt < 2; ++nt) {
        int r = wc * 64 + nt * 32 + l31;
        bfr[nt] = *(const bf16x8*)(bbuf + r * 64 + (((kt * 2 + lh) ^ (r & 3)) << 4));
      }
#pragma unroll
      for (int mt = 0; mt < 4; ++mt)
#pragma unroll
        for (int nt = 0; nt < 2; ++nt)
          acc[mt][nt] = mfma32(af[mt], bfr[nt], acc[mt][nt]);
    }
    if (kt0 < 14) {
      asm volatile("s_waitcnt vmcnt(4)" ::: "memory");
    } else if (kt0 == 14) {
      asm volatile("s_waitcnt vmcnt(0)" ::: "memory");
    }
    if (kt0 < 15) __builtin_amdgcn_s_barrier();
  }

  int nBase = bn * 256 + wc * 64;
  int mBase = bm * 256 + wr * 128;
#pragma unroll
  for (int nt = 0; nt < 2; ++nt) {
    int nn = nBase + nt * 32 + l31;
    float bs = bias[nn];
    if (MODE == 0) {
      int tsel = nn >> 9, rem = nn & 511;
      int hh = rem >> 6, d = rem & 63;
#pragma unroll
      for (int mt = 0; mt < 4; ++mt) {
#pragma unroll
        for (int q = 0; q < 4; ++q) {
          int m0 = mBase + mt * 32 + q * 8 + lh * 4;
          int r = m0 >> 8, tok = m0 & 255;
          size_t base = (size_t)(r * 8 + hh) * 16384;
          if (tsel == 0) {
#pragma unroll
            for (int j = 0; j < 4; ++j)
              qb[base + (size_t)(tok + j) * 64 + d] = f2bf((acc[mt][nt][q * 4 + j] + bs) * 0.125f);
          } else if (tsel == 1) {
#pragma unroll
            for (int j = 0; j < 4; ++j)
              kb[base + (size_t)(tok + j) * 64 + d] = f2bf(acc[mt][nt][q * 4 + j] + bs);
          } else {
            unsigned long long pv = 0;
#pragma unroll
            for (int j = 0; j < 4; ++j)
              pv |= (unsigned long long)f2bf(acc[mt][nt][q * 4 + j] + bs) << (16 * j);
            *(unsigned long long*)(vtb + base + (size_t)d * 256 + tok) = pv;
          }
        }
      }
    } else {
#pragma unroll
      for (int mt = 0; mt < 4; ++mt) {
#pragma unroll
        for (int q = 0; q < 4; ++q) {
          int m0 = mBase + mt * 32 + q * 8 + lh * 4;
          int r = m0 >> 8;
          int a = r / 12, bcol = r - a * 12;
#pragma unroll
          for (int j = 0; j < 4; ++j) {
            int tok = (m0 & 255) + j;
            int ii = tok >> 4, jj = tok & 15;
            long gg = (long)((a * 16 + ii) * 192 + bcol * 16 + jj);
            out[gg * 512 + nn] = acc[mt][nt][q * 4 + j] + bs;
          }
        }
      }
    }
  }
}

// ---------------- fused region attention v12 (unchanged from round 15) ------
// LDS: K [0,32K) | S0 [32K,64K) S1 [64K,96K) [64j][256i]swz | V0/1/2
//      [96K,120K) [64d][64j]swz | band [122880,123264). Total 123264.
__global__ __launch_bounds__(512, 2) void k_attn12(
    const unsigned short* __restrict__ qb, const unsigned short* __restrict__ kb,
    const unsigned short* __restrict__ vtb, const float* __restrict__ pe_w,
    unsigned short* __restrict__ ctxb) {
  extern __shared__ char lds[];
  int rh = blockIdx.x;
  int h = rh & 7;
  int t = threadIdx.x, w = t >> 6, lane = t & 63;
  int l31 = lane & 31, lh = lane >> 5;
  int iw = w << 5;
  int myi = iw + l31;

  const unsigned short* Qg = qb + (size_t)rh * 16384;
  const unsigned short* Kg = kb + (size_t)rh * 16384;
  const unsigned short* Vg = vtb + (size_t)rh * 16384;
  const float* wh = pe_w + h * 15;

#pragma unroll
  for (int rr = 0; rr < 4; ++rr) {
    int row = rr * 64 + (t >> 3);
    GLOAD_LDS16(Kg + row * 64 + (((t & 7) ^ (row & 7)) << 3), lds + rr * 8192 + t * 16);
  }
  {
    int row = t >> 3;
    GLOAD_LDS16(Vg + row * 256 + (((t & 7) ^ (row & 7)) << 3), lds + 98304 + t * 16);
  }
  if (t < 96) {
    int dlo = t - 40, dhi = t - 39;
    unsigned int lo = (dlo >= 0 && dlo < 15) ? f2bf(wh[dlo]) : 0;
    unsigned int hi = (dhi >= 0 && dhi < 15) ? f2bf(wh[dhi]) : 0;
    *(unsigned int*)(lds + 122880 + t * 4) = lo | (hi << 16);
  }
  bf16x8 qf[4];
#pragma unroll
  for (int kt = 0; kt < 4; ++kt)
    qf[kt] = *(const bf16x8*)(Qg + (size_t)myi * 64 + kt * 16 + lh * 8);
  __syncthreads();

  BFrag band[4];
#pragma unroll
  for (int u = 0; u < 4; ++u) {
    int d0 = 16 * u + 8 * lh - l31 + 31;
#pragma unroll
    for (int e2 = 0; e2 < 4; ++e2)
      band[u].w[e2] = *(const unsigned int*)(lds + 122880 + (d0 + 2 * e2) * 4);
  }

  float m = -3.0e38f, l = 0.0f;
  f32x16 acco[2];
#pragma unroll
  for (int nt = 0; nt < 2; ++nt)
#pragma unroll
    for (int e = 0; e < 16; ++e) acco[nt][e] = 0.0f;

#pragma unroll
  for (int tile = 0; tile < 4; ++tile) {
    char* sbuf = lds + 32768 + (tile & 1) * 32768;
    char* vbuf = lds + 98304 + (tile % 3) * 8192;

    if (tile < 3) {
      int row = t >> 3;
      GLOAD_LDS16(Vg + row * 256 + (tile + 1) * 64 + (((t & 7) ^ (row & 7)) << 3),
                  lds + 98304 + ((tile + 1) % 3) * 8192 + t * 16);
    }

    f32x16 sacc[2];
#pragma unroll
    for (int jb = 0; jb < 2; ++jb)
#pragma unroll
      for (int e = 0; e < 16; ++e) sacc[jb][e] = 0.0f;
#pragma unroll
    for (int jb = 0; jb < 2; ++jb) {
      int kr = tile * 64 + jb * 32 + l31;
#pragma unroll
      for (int kt = 0; kt < 4; ++kt) {
        bf16x8 kf = *(const bf16x8*)(lds + kr * 128 + (((kt * 2 + lh) ^ (kr & 7)) << 4));
        sacc[jb] = mfma32(kf, qf[kt], sacc[jb]);
      }
    }

    {
      int i2 = myi * 2;
#pragma unroll
      for (int jb = 0; jb < 2; ++jb)
#pragma unroll
        for (int rg = 0; rg < 16; ++rg) {
          int j = jb * 32 + (rg & 3) + 8 * (rg >> 2) + 4 * lh;
          *(unsigned short*)(sbuf + j * 512 + (i2 ^ ((j & 7) << 4))) =
              f2bf(sacc[jb][rg]);
        }
    }
    __syncthreads();

#pragma unroll
    for (int jb = 0; jb < 2; ++jb) {
      int jr = jb * 32 + l31;
#pragma unroll
      for (int u = 0; u < 4; ++u) {
        int ktg = 2 * w + u - 1;
        if (ktg >= 0 && ktg < 16) {
          bf16x8 sfr = *(const bf16x8*)(sbuf + jr * 512 +
                                        ((ktg * 32 + lh * 16) ^ ((jr & 7) << 4)));
          sacc[jb] = mfma32(sfr, band[u].v, sacc[jb]);
        }
      }
    }

    float fct;
    {
      float pm = -3.0e38f;
#pragma unroll
      for (int jb = 0; jb < 2; ++jb)
#pragma unroll
        for (int e = 0; e < 16; ++e) pm = fmaxf(pm, sacc[jb][e]);
      pm = fmaxf(pm, __shfl_xor(pm, 32));
      float mn = fmaxf(m, pm);
      float f = __expf(m - mn);
      fct = f;
      float ts = 0.0f;
#pragma unroll
      for (int jb = 0; jb < 2; ++jb)
#pragma unroll
        for (int e = 0; e < 16; ++e) {
          float p = __expf(sacc[jb][e] - mn);
          sacc[jb][e] = p;
          ts += p;
        }
      ts += __shfl_xor(ts, 32);
      l = (tile == 0) ? ts : l * f + ts;
      m = mn;
      if (tile != 0) {
#pragma unroll
        for (int rg = 0; rg < 16; ++rg) {
          float g = __shfl(fct, (rg & 3) + 8 * (rg >> 2) + 4 * lh);
          acco[0][rg] *= g;
          acco[1][rg] *= g;
        }
      }
    }

#pragma unroll
    for (int jb = 0; jb < 2; ++jb) {
      unsigned int pk[8], sw[8];
#pragma unroll
      for (int u = 0; u < 8; ++u)
        pk[u] = (unsigned int)f2bf(sacc[jb][2 * u]) |
                ((unsigned int)f2bf(sacc[jb][2 * u + 1]) << 16);
#pragma unroll
      for (int u = 0; u < 8; ++u) sw[u] = (unsigned int)__shfl_xor((int)pk[u], 32);
      BFrag pf0, pf1;
      if (lh == 0) {
        pf0.w[0] = pk[0]; pf0.w[1] = pk[1]; pf0.w[2] = sw[0]; pf0.w[3] = sw[1];
        pf1.w[0] = pk[4]; pf1.w[1] = pk[5]; pf1.w[2] = sw[4]; pf1.w[3] = sw[5];
      } else {
        pf0.w[0] = sw[2]; pf0.w[1] = sw[3]; pf0.w[2] = pk[2]; pf0.w[3] = pk[3];
        pf1.w[0] = sw[6]; pf1.w[1] = sw[7]; pf1.w[2] = pk[6]; pf1.w[3] = pk[7];
      }
#pragma unroll
      for (int nt = 0; nt < 2; ++nt) {
        int vr = nt * 32 + l31;
        int kj0 = jb * 2;
        bf16x8 vf0 = *(const bf16x8*)(vbuf + vr * 128 +
                                      (((kj0 * 2 + lh) ^ (vr & 7)) << 4));
        bf16x8 vf1 = *(const bf16x8*)(vbuf + vr * 128 +
                                      ((((kj0 + 1) * 2 + lh) ^ (vr & 7)) << 4));
        acco[nt] = mfma32(pf0.v, vf0, acco[nt]);
        acco[nt] = mfma32(pf1.v, vf1, acco[nt]);
      }
    }
  }

  float inv = 1.0f / l;
  int r256 = (rh >> 3) * 256;
  int chbase = h * 64;
#pragma unroll
  for (int rg = 0; rg < 16; ++rg) {
    int cr = (rg & 3) + 8 * (rg >> 2) + 4 * lh;
    float g = __shfl(inv, cr);
    int i = iw + cr;
    size_t rowoff = (size_t)(r256 + i) * 512 + chbase;
    ctxb[rowoff + l31] = f2bf(acco[0][rg] * g);
    ctxb[rowoff + 32 + l31] = f2bf(acco[1][rg] * g);
  }
}

extern "C" void kernel_launch(void* const* d_in, const int* in_sizes, int n_in,
                              void* d_out, int out_size, void* d_ws, size_t ws_size,
                              hipStream_t stream) {
  const float* x = (const float*)d_in[0];
  const float* Wqkv = (const float*)d_in[1];
  const float* bqkv = (const float*)d_in[2];
  const float* Wproj = (const float*)d_in[3];
  const float* bproj = (const float*)d_in[4];
  const float* pew = (const float*)d_in[5];
  // d_in[6] = pe_b: constant per softmax row -> cancels exactly; skipped.

  char* ws = (char*)d_ws;
  unsigned short* xb = (unsigned short*)ws;                       // later reused as ctx
  unsigned short* wqkvb = (unsigned short*)(ws + 37748736);
  unsigned short* wprojb = (unsigned short*)(ws + 39321600);
  unsigned short* qb = (unsigned short*)(ws + 39845888);
  unsigned short* kb = (unsigned short*)(ws + 77594624);
  unsigned short* vtb = (unsigned short*)(ws + 115343360);

  (void)hipFuncSetAttribute((const void*)k_attn12,
                            hipFuncAttributeMaxDynamicSharedMemorySize, 163840);
  (void)hipFuncSetAttribute((const void*)k_gemm2<0, 6>,
                            hipFuncAttributeMaxDynamicSharedMemorySize, 131072);
  (void)hipFuncSetAttribute((const void*)k_gemm2<1, 2>,
                            hipFuncAttributeMaxDynamicSharedMemorySize, 131072);

  k_xgather<<<9216, 256, 0, stream>>>(x, xb);
  k_cvt<<<384, 256, 0, stream>>>(Wqkv, wqkvb, 98304);
  k_cvt<<<128, 256, 0, stream>>>(Wproj, wprojb, 32768);
  k_gemm2<0, 6><<<864, 512, 131072, stream>>>(xb, wqkvb, bqkv, qb, kb, vtb, nullptr);
  k_attn12<<<1152, 512, 123264, stream>>>(qb, kb, vtb, pew, xb);
  k_gemm2<1, 2><<<288, 512, 131072, stream>>>(xb, wprojb, bproj, nullptr, nullptr, nullptr,
                                              (float*)d_out);
}

// Round 17
// 219.614 us; speedup vs baseline: 1.1207x; 1.1207x over previous
//
#include <hip/hip_runtime.h>
#include <stdint.h>

typedef __attribute__((ext_vector_type(8))) __bf16 bf16x8;
typedef __attribute__((ext_vector_type(16))) float f32x16;

__device__ __forceinline__ unsigned short f2bf(float f) {
  union { float f; unsigned int u; } v;
  v.f = f;
  unsigned int u = v.u;
  return (unsigned short)((u + 0x7FFFu + ((u >> 16) & 1u)) >> 16);
}

union BFrag { unsigned short u[8]; unsigned int w[4]; bf16x8 v; };

__device__ __forceinline__ f32x16 mfma32(bf16x8 a, bf16x8 b, f32x16 c) {
  return __builtin_amdgcn_mfma_f32_32x32x16_bf16(a, b, c, 0, 0, 0);
}

#define GLOAD_LDS16(gptr, lptr)                                                \
  __builtin_amdgcn_global_load_lds(                                           \
      (const __attribute__((address_space(1))) void*)(gptr),                  \
      (__attribute__((address_space(3))) void*)(lptr), 16, 0, 0)

// ---------------- x gather + fp32->bf16 (region-token order) ----------------
__global__ __launch_bounds__(256) void k_xgather(const float* __restrict__ x,
                                                 unsigned short* __restrict__ xb) {
  int idx = blockIdx.x * 256 + threadIdx.x;
  int m = idx >> 6;
  int seg = (idx & 63) << 3;
  int r = m >> 8, n = m & 255;
  int a = r / 12, b = r - a * 12;
  int ii = n >> 4, jj = n & 15;
  long g = (long)((a * 16 + ii) * 192 + b * 16 + jj);
  const float4* p = (const float4*)(x + g * 512 + seg);
  float4 v0 = p[0], v1 = p[1];
  union { unsigned short u[8]; int4 v; } o;
  o.u[0] = f2bf(v0.x); o.u[1] = f2bf(v0.y); o.u[2] = f2bf(v0.z); o.u[3] = f2bf(v0.w);
  o.u[4] = f2bf(v1.x); o.u[5] = f2bf(v1.y); o.u[6] = f2bf(v1.z); o.u[7] = f2bf(v1.w);
  *(int4*)(xb + (size_t)m * 512 + seg) = o.v;
}

// ---------------- plain fp32->bf16 ----------------
__global__ __launch_bounds__(256) void k_cvt(const float* __restrict__ s,
                                             unsigned short* __restrict__ d, int n8) {
  int i = blockIdx.x * 256 + threadIdx.x;
  if (i >= n8) return;
  const float4* p = (const float4*)(s + (size_t)i * 8);
  float4 a = p[0], b = p[1];
  union { unsigned short u[8]; int4 v; } o;
  o.u[0] = f2bf(a.x); o.u[1] = f2bf(a.y); o.u[2] = f2bf(a.z); o.u[3] = f2bf(a.w);
  o.u[4] = f2bf(b.x); o.u[5] = f2bf(b.y); o.u[6] = f2bf(b.z); o.u[7] = f2bf(b.w);
  *(int4*)(d + (size_t)i * 8) = o.v;
}

// ---------------- GEMM (m97-style; q scaled by 1/8, natural-domain softmax) ----
template<int MODE, int NBN>
__global__ __launch_bounds__(256, 2) void k_gemm(
    const unsigned short* __restrict__ A, const unsigned short* __restrict__ B,
    const float* __restrict__ bias,
    unsigned short* __restrict__ qb, unsigned short* __restrict__ kb,
    unsigned short* __restrict__ vtb, float* __restrict__ out) {
  __shared__ unsigned short As[8192];
  __shared__ unsigned short Bs[8192];
  int t = threadIdx.x;
  constexpr int NWG = NBN * 288;
  int d0 = blockIdx.x;
  int tl = (d0 & 7) * (NWG >> 3) + (d0 >> 3);
  int bm = tl / NBN, bn = tl % NBN;

  int w = t >> 6, lane = t & 63;
  int l31 = lane & 31, lh = lane >> 5;
  int wr = w >> 1, wc = w & 1;

  int srow = t >> 3, cseg = t & 7;
  int csw = (cseg ^ (srow & 7)) << 3;
  int ldsWaveOff = (t >> 6) << 10;

  f32x16 acc[2][2];
  for (int i = 0; i < 2; ++i)
    for (int j = 0; j < 2; ++j)
      for (int e = 0; e < 16; ++e) acc[i][j][e] = 0.0f;

  const unsigned short* Ag = A + (size_t)(bm * 128 + srow) * 512 + csw;
  const unsigned short* Bg = B + (size_t)(bn * 128 + srow) * 512 + csw;

  for (int ks = 0; ks < 8; ++ks) {
#pragma unroll
    for (int rnd = 0; rnd < 4; ++rnd) {
      GLOAD_LDS16(Ag + (size_t)rnd * 32 * 512 + ks * 64,
                  (char*)As + ldsWaveOff + rnd * 4096);
      GLOAD_LDS16(Bg + (size_t)rnd * 32 * 512 + ks * 64,
                  (char*)Bs + ldsWaveOff + rnd * 4096);
    }
    __syncthreads();
#pragma unroll
    for (int kt = 0; kt < 4; ++kt) {
      bf16x8 af[2], bfr[2];
#pragma unroll
      for (int mt = 0; mt < 2; ++mt) {
        int r = wr * 64 + mt * 32 + l31;
        af[mt] = *(const bf16x8*)((const char*)As + r * 128 +
                                  ((kt * 32 + lh * 16) ^ ((r & 7) << 4)));
      }
#pragma unroll
      for (int nt = 0; nt < 2; ++nt) {
        int r = wc * 64 + nt * 32 + l31;
        bfr[nt] = *(const bf16x8*)((const char*)Bs + r * 128 +
                                   ((kt * 32 + lh * 16) ^ ((r & 7) << 4)));
      }
#pragma unroll
      for (int mt = 0; mt < 2; ++mt)
#pragma unroll
        for (int nt = 0; nt < 2; ++nt)
          acc[mt][nt] = mfma32(af[mt], bfr[nt], acc[mt][nt]);
    }
    __syncthreads();
  }

  int nBase = bn * 128 + wc * 64;
  int mBase = bm * 128 + wr * 64;
#pragma unroll
  for (int nt = 0; nt < 2; ++nt) {
    int nn = nBase + nt * 32 + l31;
    float bs = bias[nn];
    if (MODE == 0) {
      int tsel = nn >> 9, rem = nn & 511;
      int hh = rem >> 6, d = rem & 63;
#pragma unroll
      for (int mt = 0; mt < 2; ++mt) {
#pragma unroll
        for (int q = 0; q < 4; ++q) {
          int m0 = mBase + mt * 32 + q * 8 + lh * 4;
          int r = m0 >> 8, tok = m0 & 255;
          size_t base = (size_t)(r * 8 + hh) * 16384;
          if (tsel == 0) {
#pragma unroll
            for (int j = 0; j < 4; ++j)
              qb[base + (size_t)(tok + j) * 64 + d] = f2bf((acc[mt][nt][q * 4 + j] + bs) * 0.125f);
          } else if (tsel == 1) {
#pragma unroll
            for (int j = 0; j < 4; ++j)
              kb[base + (size_t)(tok + j) * 64 + d] = f2bf(acc[mt][nt][q * 4 + j] + bs);
          } else {
            unsigned long long pv = 0;
#pragma unroll
            for (int j = 0; j < 4; ++j)
              pv |= (unsigned long long)f2bf(acc[mt][nt][q * 4 + j] + bs) << (16 * j);
            *(unsigned long long*)(vtb + base + (size_t)d * 256 + tok) = pv;
          }
        }
      }
    } else {
#pragma unroll
      for (int mt = 0; mt < 2; ++mt) {
#pragma unroll
        for (int q = 0; q < 4; ++q) {
          int m0 = mBase + mt * 32 + q * 8 + lh * 4;
          int r = m0 >> 8;
          int a = r / 12, bcol = r - a * 12;
#pragma unroll
          for (int j = 0; j < 4; ++j) {
            int tok = (m0 & 255) + j;
            int ii = tok >> 4, jj = tok & 15;
            long gg = (long)((a * 16 + ii) * 192 + bcol * 16 + jj);
            out[gg * 512 + nn] = acc[mt][nt][q * 4 + j] + bs;
          }
        }
      }
    }
  }
}

// ---------------- fused region attention v12: v5 + 1 barrier/tile + band regs
// Structure/numerics = v5 (8 waves x 32 rows, KVBLK=64, (512,2), natural __expf,
// always-rescale, f2bf). Changes: S^T double-buffered (2x32K), V triple-
// buffered (3x8K, staged one iter early), band table hoisted to 4 BFrag regs.
// Barriers/block: 9 -> 5.
// LDS: K [0,32K) | S0 [32K,64K) S1 [64K,96K) [64j][256i]swz | V0/1/2
//      [96K,120K) [64d][64j]swz | band [122880,123264). Total 123264.
__global__ __launch_bounds__(512, 2) void k_attn12(
    const unsigned short* __restrict__ qb, const unsigned short* __restrict__ kb,
    const unsigned short* __restrict__ vtb, const float* __restrict__ pe_w,
    unsigned short* __restrict__ ctxb) {
  extern __shared__ char lds[];
  int rh = blockIdx.x;
  int h = rh & 7;
  int t = threadIdx.x, w = t >> 6, lane = t & 63;
  int l31 = lane & 31, lh = lane >> 5;
  int iw = w << 5;
  int myi = iw + l31;

  const unsigned short* Qg = qb + (size_t)rh * 16384;
  const unsigned short* Kg = kb + (size_t)rh * 16384;
  const unsigned short* Vg = vtb + (size_t)rh * 16384;
  const float* wh = pe_w + h * 15;

  // ---- stage K (4 rounds x 64 rows x 128B) + V tile0 + band table ----
#pragma unroll
  for (int rr = 0; rr < 4; ++rr) {
    int row = rr * 64 + (t >> 3);
    GLOAD_LDS16(Kg + row * 64 + (((t & 7) ^ (row & 7)) << 3), lds + rr * 8192 + t * 16);
  }
  {
    int row = t >> 3;
    GLOAD_LDS16(Vg + row * 256 + (((t & 7) ^ (row & 7)) << 3), lds + 98304 + t * 16);
  }
  if (t < 96) {
    int dlo = t - 40, dhi = t - 39;
    unsigned int lo = (dlo >= 0 && dlo < 15) ? f2bf(wh[dlo]) : 0;
    unsigned int hi = (dhi >= 0 && dhi < 15) ? f2bf(wh[dhi]) : 0;
    *(unsigned int*)(lds + 122880 + t * 4) = lo | (hi << 16);
  }
  // ---- Q fragments direct to regs (pre-scaled by 1/8 in gemm epilogue) ----
  bf16x8 qf[4];
#pragma unroll
  for (int kt = 0; kt < 4; ++kt)
    qf[kt] = *(const bf16x8*)(Qg + (size_t)myi * 64 + kt * 16 + lh * 8);
  __syncthreads();   // K, V0, band staged

  // ---- band fragments hoisted to registers (tile- and jb-invariant) ----
  BFrag band[4];
#pragma unroll
  for (int u = 0; u < 4; ++u) {
    int d0 = 16 * u + 8 * lh - l31 + 31;   // == ktg*16+lh*8-myi+47, ktg=2w+u-1
#pragma unroll
    for (int e2 = 0; e2 < 4; ++e2)
      band[u].w[e2] = *(const unsigned int*)(lds + 122880 + (d0 + 2 * e2) * 4);
  }

  float m = -3.0e38f, l = 0.0f;
  f32x16 acco[2];
#pragma unroll
  for (int nt = 0; nt < 2; ++nt)
#pragma unroll
    for (int e = 0; e < 16; ++e) acco[nt][e] = 0.0f;

#pragma unroll
  for (int tile = 0; tile < 4; ++tile) {
    char* sbuf = lds + 32768 + (tile & 1) * 32768;
    char* vbuf = lds + 98304 + (tile % 3) * 8192;

    // ---- issue V(tile+1) early: latency hides under QK + S^T store ----
    if (tile < 3) {
      int row = t >> 3;
      GLOAD_LDS16(Vg + row * 256 + (tile + 1) * 64 + (((t & 7) ^ (row & 7)) << 3),
                  lds + 98304 + ((tile + 1) % 3) * 8192 + t * 16);
    }

    // ---- QK^T for this j-tile: sacc[jb] rows j (reg), cols i (lane) ----
    f32x16 sacc[2];
#pragma unroll
    for (int jb = 0; jb < 2; ++jb)
#pragma unroll
      for (int e = 0; e < 16; ++e) sacc[jb][e] = 0.0f;
#pragma unroll
    for (int jb = 0; jb < 2; ++jb) {
      int kr = tile * 64 + jb * 32 + l31;
#pragma unroll
      for (int kt = 0; kt < 4; ++kt) {
        bf16x8 kf = *(const bf16x8*)(lds + kr * 128 + (((kt * 2 + lh) ^ (kr & 7)) << 4));
        sacc[jb] = mfma32(kf, qf[kt], sacc[jb]);
      }
    }

    // ---- store S^T tile to sbuf (bf16 via f2bf/RNE, XOR-swizzled) ----
    {
      int i2 = myi * 2;
#pragma unroll
      for (int jb = 0; jb < 2; ++jb)
#pragma unroll
        for (int rg = 0; rg < 16; ++rg) {
          int j = jb * 32 + (rg & 3) + 8 * (rg >> 2) + 4 * lh;
          *(unsigned short*)(sbuf + j * 512 + (i2 ^ ((j & 7) << 4))) =
              f2bf(sacc[jb][rg]);
        }
    }
    __syncthreads();   // S^T(t) visible; V(t) drained (issued last iter)

    // ---- banded conv: sacc += S^T-tile x Wband (band in regs) ----
#pragma unroll
    for (int jb = 0; jb < 2; ++jb) {
      int jr = jb * 32 + l31;
#pragma unroll
      for (int u = 0; u < 4; ++u) {
        int ktg = 2 * w + u - 1;
        if (ktg >= 0 && ktg < 16) {
          bf16x8 sfr = *(const bf16x8*)(sbuf + jr * 512 +
                                        ((ktg * 32 + lh * 16) ^ ((jr & 7) << 4)));
          sacc[jb] = mfma32(sfr, band[u].v, sacc[jb]);
        }
      }
    }

    // ---- exact online softmax (natural domain, always rescale) ----
    float fct;
    {
      float pm = -3.0e38f;
#pragma unroll
      for (int jb = 0; jb < 2; ++jb)
#pragma unroll
        for (int e = 0; e < 16; ++e) pm = fmaxf(pm, sacc[jb][e]);
      pm = fmaxf(pm, __shfl_xor(pm, 32));
      float mn = fmaxf(m, pm);
      float f = __expf(m - mn);
      fct = f;
      float ts = 0.0f;
#pragma unroll
      for (int jb = 0; jb < 2; ++jb)
#pragma unroll
        for (int e = 0; e < 16; ++e) {
          float p = __expf(sacc[jb][e] - mn);
          sacc[jb][e] = p;
          ts += p;
        }
      ts += __shfl_xor(ts, 32);
      l = (tile == 0) ? ts : l * f + ts;
      m = mn;
      if (tile != 0) {
#pragma unroll
        for (int rg = 0; rg < 16; ++rg) {
          float g = __shfl(fct, (rg & 3) + 8 * (rg >> 2) + 4 * lh);
          acco[0][rg] *= g;
          acco[1][rg] *= g;
        }
      }
    }

    // ---- PV: pack P to bf16 A-frags (lh-swap) and MFMA with V-tile ----
#pragma unroll
    for (int jb = 0; jb < 2; ++jb) {
      unsigned int pk[8], sw[8];
#pragma unroll
      for (int u = 0; u < 8; ++u)
        pk[u] = (unsigned int)f2bf(sacc[jb][2 * u]) |
                ((unsigned int)f2bf(sacc[jb][2 * u + 1]) << 16);
#pragma unroll
      for (int u = 0; u < 8; ++u) sw[u] = (unsigned int)__shfl_xor((int)pk[u], 32);
      BFrag pf0, pf1;
      if (lh == 0) {
        pf0.w[0] = pk[0]; pf0.w[1] = pk[1]; pf0.w[2] = sw[0]; pf0.w[3] = sw[1];
        pf1.w[0] = pk[4]; pf1.w[1] = pk[5]; pf1.w[2] = sw[4]; pf1.w[3] = sw[5];
      } else {
        pf0.w[0] = sw[2]; pf0.w[1] = sw[3]; pf0.w[2] = pk[2]; pf0.w[3] = pk[3];
        pf1.w[0] = sw[6]; pf1.w[1] = sw[7]; pf1.w[2] = pk[6]; pf1.w[3] = pk[7];
      }
#pragma unroll
      for (int nt = 0; nt < 2; ++nt) {
        int vr = nt * 32 + l31;
        int kj0 = jb * 2;
        bf16x8 vf0 = *(const bf16x8*)(vbuf + vr * 128 +
                                      (((kj0 * 2 + lh) ^ (vr & 7)) << 4));
        bf16x8 vf1 = *(const bf16x8*)(vbuf + vr * 128 +
                                      ((((kj0 + 1) * 2 + lh) ^ (vr & 7)) << 4));
        acco[nt] = mfma32(pf0.v, vf0, acco[nt]);
        acco[nt] = mfma32(pf1.v, vf1, acco[nt]);
      }
    }
  }

  // ---- epilogue: normalize by 1/l and store ----
  float inv = 1.0f / l;
  int r256 = (rh >> 3) * 256;
  int chbase = h * 64;
#pragma unroll
  for (int rg = 0; rg < 16; ++rg) {
    int cr = (rg & 3) + 8 * (rg >> 2) + 4 * lh;
    float g = __shfl(inv, cr);
    int i = iw + cr;
    size_t rowoff = (size_t)(r256 + i) * 512 + chbase;
    ctxb[rowoff + l31] = f2bf(acco[0][rg] * g);
    ctxb[rowoff + 32 + l31] = f2bf(acco[1][rg] * g);
  }
}

extern "C" void kernel_launch(void* const* d_in, const int* in_sizes, int n_in,
                              void* d_out, int out_size, void* d_ws, size_t ws_size,
                              hipStream_t stream) {
  const float* x = (const float*)d_in[0];
  const float* Wqkv = (const float*)d_in[1];
  const float* bqkv = (const float*)d_in[2];
  const float* Wproj = (const float*)d_in[3];
  const float* bproj = (const float*)d_in[4];
  const float* pew = (const float*)d_in[5];
  // d_in[6] = pe_b: constant per softmax row -> cancels exactly; skipped.

  char* ws = (char*)d_ws;
  unsigned short* xb = (unsigned short*)ws;                       // later reused as ctx
  unsigned short* wqkvb = (unsigned short*)(ws + 37748736);
  unsigned short* wprojb = (unsigned short*)(ws + 39321600);
  unsigned short* qb = (unsigned short*)(ws + 39845888);
  unsigned short* kb = (unsigned short*)(ws + 77594624);
  unsigned short* vtb = (unsigned short*)(ws + 115343360);

  (void)hipFuncSetAttribute((const void*)k_attn12,
                            hipFuncAttributeMaxDynamicSharedMemorySize, 163840);

  k_xgather<<<9216, 256, 0, stream>>>(x, xb);
  k_cvt<<<384, 256, 0, stream>>>(Wqkv, wqkvb, 98304);
  k_cvt<<<128, 256, 0, stream>>>(Wproj, wprojb, 32768);
  k_gemm<0, 12><<<3456, 256, 0, stream>>>(xb, wqkvb, bqkv, qb, kb, vtb, nullptr);
  k_attn12<<<1152, 512, 123264, stream>>>(qb, kb, vtb, pew, xb);
  k_gemm<1, 4><<<1152, 256, 0, stream>>>(xb, wprojb, bproj, nullptr, nullptr, nullptr,
                                         (float*)d_out);
}